// Round 1
// baseline (552.039 us; speedup 1.0000x reference)
//
#include <hip/hip_runtime.h>

#define DEVINL __device__ __forceinline__

typedef __attribute__((ext_vector_type(8))) short bf16x8;
typedef __attribute__((ext_vector_type(4))) float f32x4;

static constexpr int S = 4096;
static constexpr int D = 768;
static constexpr float POST_SCALE = 19.595917942265423f; // sqrt(384)

#define MFMA16(a, b, c) __builtin_amdgcn_mfma_f32_16x16x32_bf16((a), (b), (c), 0, 0, 0)

DEVINL unsigned short f2bf(float f) {
  union { float f; unsigned u; } v; v.f = f;
  unsigned r = (v.u + 0x7FFFu + ((v.u >> 16) & 1u)) >> 16;  // RNE
  return (unsigned short)r;
}

// ---------------- fp32 -> bf16 convert ----------------
__global__ void cvt_kernel(const float* __restrict__ src,
                           unsigned short* __restrict__ dst, int n4) {
  int i = blockIdx.x * blockDim.x + threadIdx.x;
  if (i >= n4) return;
  float4 v = reinterpret_cast<const float4*>(src)[i];
  ushort4 o;
  o.x = f2bf(v.x); o.y = f2bf(v.y); o.z = f2bf(v.z); o.w = f2bf(v.w);
  reinterpret_cast<ushort4*>(dst)[i] = o;
}

// ---------------- (a+b) fp32 -> bf16 ----------------
__global__ void addcvt_kernel(const float* __restrict__ a,
                              const float* __restrict__ b,
                              unsigned short* __restrict__ dst, int n4) {
  int i = blockIdx.x * blockDim.x + threadIdx.x;
  if (i >= n4) return;
  float4 va = reinterpret_cast<const float4*>(a)[i];
  float4 vb = reinterpret_cast<const float4*>(b)[i];
  ushort4 o;
  o.x = f2bf(va.x + vb.x); o.y = f2bf(va.y + vb.y);
  o.z = f2bf(va.z + vb.z); o.w = f2bf(va.w + vb.w);
  reinterpret_cast<ushort4*>(dst)[i] = o;
}

// ---------------- bf16 transpose [S,D] -> [D,S] ----------------
__global__ void transpose_kernel(const unsigned short* __restrict__ in,
                                 unsigned short* __restrict__ out) {
  __shared__ unsigned short tile[32][33];
  int d0 = blockIdx.x * 32, t0 = blockIdx.y * 32;
  int tx = threadIdx.x, ty = threadIdx.y;  // block (32,8)
#pragma unroll
  for (int j = 0; j < 4; j++)
    tile[ty + j * 8][tx] = in[(size_t)(t0 + ty + j * 8) * D + d0 + tx];
  __syncthreads();
#pragma unroll
  for (int j = 0; j < 4; j++)
    out[(size_t)(d0 + ty + j * 8) * S + t0 + tx] = tile[tx][ty + j * 8];
}

// ---------------- GEMM: C[M,N] = A[M,K] @ B[N,K]^T + bias ----------------
// A, B bf16 row-major; direct-global MFMA fragments (no LDS staging, round 0).
// block = 256 thr (4 waves), tile 128x128, each wave 64x64 (4x4 fragments).
template <bool F32OUT>
__global__ __launch_bounds__(256) void gemm_bt(
    const unsigned short* __restrict__ A, const unsigned short* __restrict__ B,
    const float* __restrict__ bias, void* __restrict__ Cout,
    int M, int N, int K) {
  int w = threadIdx.x >> 6, lane = threadIdx.x & 63;
  int r = lane & 15, b = lane >> 4;
  int rowbase = blockIdx.y * 128 + (w >> 1) * 64;
  int colbase = blockIdx.x * 128 + (w & 1) * 64;
  f32x4 acc[4][4] = {};
  for (int kk = 0; kk < K; kk += 32) {
    bf16x8 af[4], bfr[4];
#pragma unroll
    for (int m = 0; m < 4; m++)
      af[m] = *reinterpret_cast<const bf16x8*>(A + (size_t)(rowbase + m * 16 + r) * K + kk + b * 8);
#pragma unroll
    for (int n = 0; n < 4; n++)
      bfr[n] = *reinterpret_cast<const bf16x8*>(B + (size_t)(colbase + n * 16 + r) * K + kk + b * 8);
#pragma unroll
    for (int m = 0; m < 4; m++)
#pragma unroll
      for (int n = 0; n < 4; n++)
        acc[m][n] = MFMA16(af[m], bfr[n], acc[m][n]);
  }
#pragma unroll
  for (int m = 0; m < 4; m++)
#pragma unroll
    for (int n = 0; n < 4; n++)
#pragma unroll
      for (int i = 0; i < 4; i++) {
        int row = rowbase + m * 16 + b * 4 + i;
        int col = colbase + n * 16 + r;
        float v = acc[m][n][i] + bias[col];
        if (F32OUT)
          reinterpret_cast<float*>(Cout)[(size_t)row * N + col] = v;
        else
          reinterpret_cast<unsigned short*>(Cout)[(size_t)row * N + col] = f2bf(v);
      }
}

// ---------------- fused attention ----------------
// scores[h,s,t] = K_s^h . Q_t^h ; softmax over h (12 vals, pointwise-local);
// O[h,s,:] += P[h,s,t] * V[t,:].  Block: 16 s-rows x all 12 heads, 4 waves
// (3 heads each), loops t in chunks of 32 over its half of [0,4096).
__global__ __launch_bounds__(256) void attn_kernel(
    const unsigned short* __restrict__ Qb, const unsigned short* __restrict__ Kb,
    const unsigned short* __restrict__ Vt, float* __restrict__ Opart) {
  __shared__ float Slds[12][16][32];          // 24 KB
  __shared__ unsigned short Plds[12][16][40]; // 15 KB (pad 32->40 for PV reads)

  int s0 = blockIdx.x * 16;
  int th = blockIdx.y;  // t-half: [th*2048, th*2048+2048)
  int w = threadIdx.x >> 6, lane = threadIdx.x & 63;
  int r = lane & 15, b = lane >> 4;

  // K fragments for this block's 16 s-rows (constant over t loop)
  bf16x8 kf[3][2];
#pragma unroll
  for (int hh = 0; hh < 3; hh++) {
    int h = w * 3 + hh;
#pragma unroll
    for (int ks = 0; ks < 2; ks++)
      kf[hh][ks] = *reinterpret_cast<const bf16x8*>(
          Kb + (size_t)(s0 + r) * D + h * 64 + ks * 32 + b * 8);
  }

  f32x4 oacc[3][4] = {};

  int tbeg = th * 2048, tend = tbeg + 2048;
  for (int t0 = tbeg; t0 < tend; t0 += 32) {
    // ---- scores for 3 heads per wave ----
#pragma unroll
    for (int hh = 0; hh < 3; hh++) {
      int h = w * 3 + hh;
#pragma unroll
      for (int ts = 0; ts < 2; ts++) {
        f32x4 c = {};
#pragma unroll
        for (int ks = 0; ks < 2; ks++) {
          bf16x8 qf = *reinterpret_cast<const bf16x8*>(
              Qb + (size_t)(t0 + ts * 16 + r) * D + h * 64 + ks * 32 + b * 8);
          c = MFMA16(kf[hh][ks], qf, c);
        }
#pragma unroll
        for (int i = 0; i < 4; i++)
          Slds[h][b * 4 + i][ts * 16 + r] = c[i];
      }
    }
    __syncthreads();

    // ---- pointwise softmax over heads (12 vals per (s,t)) ----
    for (int p = threadIdx.x; p < 512; p += 256) {
      int sr = p >> 5, tc = p & 31;
      float v[12];
      float m = -1e30f;
#pragma unroll
      for (int h = 0; h < 12; h++) { v[h] = Slds[h][sr][tc]; m = fmaxf(m, v[h]); }
      float sum = 0.f;
#pragma unroll
      for (int h = 0; h < 12; h++) { v[h] = __expf(v[h] - m); sum += v[h]; }
      float sc = POST_SCALE / sum;
#pragma unroll
      for (int h = 0; h < 12; h++) Plds[h][sr][tc] = f2bf(v[h] * sc);
    }
    __syncthreads();

    // ---- PV: O[h][16s][64d] += P[h][16s][32t] @ V[32t][64d] ----
#pragma unroll
    for (int hh = 0; hh < 3; hh++) {
      int h = w * 3 + hh;
      bf16x8 pf = *reinterpret_cast<const bf16x8*>(&Plds[h][r][b * 8]);
#pragma unroll
      for (int ds = 0; ds < 4; ds++) {
        bf16x8 vf = *reinterpret_cast<const bf16x8*>(
            Vt + (size_t)(h * 64 + ds * 16 + r) * S + t0 + b * 8);
        oacc[hh][ds] = MFMA16(pf, vf, oacc[hh][ds]);
      }
    }
    __syncthreads();  // protect Slds/Plds before next chunk
  }

  float* Op = Opart + (size_t)th * S * D;
#pragma unroll
  for (int hh = 0; hh < 3; hh++)
#pragma unroll
    for (int ds = 0; ds < 4; ds++)
#pragma unroll
      for (int i = 0; i < 4; i++) {
        int row = s0 + b * 4 + i;
        int col = (w * 3 + hh) * 64 + ds * 16 + r;
        Op[(size_t)row * D + col] = oacc[hh][ds][i];
      }
}

extern "C" void kernel_launch(void* const* d_in, const int* in_sizes, int n_in,
                              void* d_out, int out_size, void* d_ws, size_t ws_size,
                              hipStream_t stream) {
  const float* x  = (const float*)d_in[0];
  const float* Wq = (const float*)d_in[1];
  const float* bq = (const float*)d_in[2];
  const float* Wk = (const float*)d_in[3];
  const float* bk = (const float*)d_in[4];
  const float* Wv = (const float*)d_in[5];
  const float* bv = (const float*)d_in[6];
  const float* Wo = (const float*)d_in[7];
  const float* bo = (const float*)d_in[8];
  float* out = (float*)d_out;

  char* ws = (char*)d_ws;
  size_t off = 0;
  auto walloc = [&](size_t bytes) -> void* {
    void* p = ws + off;
    off += (bytes + 255) & ~(size_t)255;
    return p;
  };
  unsigned short* xb  = (unsigned short*)walloc((size_t)S * D * 2);
  unsigned short* Wqb = (unsigned short*)walloc((size_t)D * D * 2);
  unsigned short* Wkb = (unsigned short*)walloc((size_t)D * D * 2);
  unsigned short* Wvb = (unsigned short*)walloc((size_t)D * D * 2);
  unsigned short* Wob = (unsigned short*)walloc((size_t)D * D * 2);
  unsigned short* Qb  = (unsigned short*)walloc((size_t)S * D * 2);
  unsigned short* Kb  = (unsigned short*)walloc((size_t)S * D * 2);
  unsigned short* Vb  = (unsigned short*)walloc((size_t)S * D * 2);
  unsigned short* Vt  = (unsigned short*)walloc((size_t)S * D * 2);
  unsigned short* Ob  = (unsigned short*)walloc((size_t)S * D * 2);
  float* Opart = (float*)walloc((size_t)2 * S * D * 4);

  int n4;
  n4 = S * D / 4;
  cvt_kernel<<<(n4 + 255) / 256, 256, 0, stream>>>(x, xb, n4);
  n4 = D * D / 4;
  cvt_kernel<<<(n4 + 255) / 256, 256, 0, stream>>>(Wq, Wqb, n4);
  cvt_kernel<<<(n4 + 255) / 256, 256, 0, stream>>>(Wk, Wkb, n4);
  cvt_kernel<<<(n4 + 255) / 256, 256, 0, stream>>>(Wv, Wvb, n4);
  cvt_kernel<<<(n4 + 255) / 256, 256, 0, stream>>>(Wo, Wob, n4);

  dim3 gg(D / 128, S / 128);  // (6, 32)
  gemm_bt<false><<<gg, 256, 0, stream>>>(xb, Wqb, bq, Qb, S, D, D);
  gemm_bt<false><<<gg, 256, 0, stream>>>(xb, Wkb, bk, Kb, S, D, D);
  gemm_bt<false><<<gg, 256, 0, stream>>>(xb, Wvb, bv, Vb, S, D, D);

  transpose_kernel<<<dim3(D / 32, S / 32), dim3(32, 8), 0, stream>>>(Vb, Vt);

  attn_kernel<<<dim3(S / 16, 2), 256, 0, stream>>>(Qb, Kb, Vt, Opart);

  n4 = S * D / 4;
  addcvt_kernel<<<(n4 + 255) / 256, 256, 0, stream>>>(Opart, Opart + (size_t)S * D, Ob, n4);

  gemm_bt<true><<<gg, 256, 0, stream>>>(Ob, Wob, bo, out, S, D, D);
}